// Round 1
// baseline (502.958 us; speedup 1.0000x reference)
//
#include <hip/hip_runtime.h>
#include <stdint.h>
#include <stddef.h>

// Bit-exact emulation of the reference's f32/f64 rounding. Contraction would
// change rounding of the literal f32 chains -> force it off globally.
#pragma clang fp contract(off)

typedef unsigned int u32;
typedef unsigned long long u64;

// ===========================================================================
// Validated machinery (rounds 2-4): state bits in {Z=0, O=1, W=1-2^-24},
// packed (hard,dirty) masks; f0 classes {Z,O,W,W2,W4,T,U,E} as planes
// Mh/QA/QB/QC/Re (v = h + (QA+2QB+4QC-4)*2^-24 - Re*2^-48).
//
// Round-6 fix: round 5's chain_slow computed __builtin_ctz(0) for lanes with
// no E bit that were dragged down the slow path by the wave ballot (UB ->
// v_ffbl returns -1 -> garbage). kE = (ReL==0) ? 29 : ctz(ReL); the prefix
// formula at kE=29 degenerates exactly to chain_fast.
//
// Round-7 change (occupancy): LDS was 40 KB/block -> 20 KB/wave -> only
// 8 waves/CU (25%), while VGPR=128 permits 16 waves/CU. The three dirty-mask
// planes (24 KB/block) move to per-thread scratch (192 B/lane, runtime-indexed
// local arrays -> private segment, lane-interleaved = coalesced, L2-resident).
// lds_wv stays in LDS (16 KB/block = 8 KB/wave). Occupancy cap 8 -> 16
// waves/CU; __launch_bounds__(128,4) pins VGPR <= 128.
// ===========================================================================

__device__ __forceinline__ u32 rotl32(u32 x, u32 n) {
    return (x << n) | (x >> (32u - n));
}

#define WF   0x1.fffffep-1f   /* w  = 1-2^-24 */
#define TWOW 0x1.fffffep+0f   /* 2w = 2-2^-23 */

// dirty flags for soft_add32(x, y) with raw float y, x in {0,1,w}
__device__ __forceinline__ u32 dirty0(float y) {
#pragma clang fp contract(off)
    float p = 0.5f * y;
    float t = 1.0f + p;
    return (u32)((t - p) != 1.0f);
}
__device__ __forceinline__ u32 dirty1(float y) {
#pragma clang fp contract(off)
    float u = 1.0f + y;
    float v = y + y;
    float xr = u - v;
    float p = 0.5f * xr;
    float t = 1.0f + p;
    return (u32)((t - p) != 1.0f);
}
__device__ __forceinline__ u32 dirtyw(float y) {
#pragma clang fp contract(off)
    float u = WF + y;
    float v = TWOW * y;
    float xr = u - v;
    float p = 0.5f * xr;
    float t = 1.0f + p;
    return (u32)((t - p) != 1.0f);
}

// Sequential f64 bit-sum of a packed {0,1,w} word (validated).
__device__ __forceinline__ double sum_packed(u32 h, u32 d) {
#pragma clang fp contract(off)
    double s = fma((double)(d & 0x1FFFFFFFu), -0x1p-24,
                   (double)(h & 0x1FFFFFFFu));
    int n29 = (int)(((h >> 29) & 1u) << 24) - (int)((d >> 29) & 1u);
    s = fma((double)n29, 0x1p5, s);
    int n30 = (int)(((h >> 30) & 1u) << 24) - (int)((d >> 30) & 1u);
    s = fma((double)n30, 0x1p6, s);
    int n31 = (int)((h >> 31) << 24) - (int)(d >> 31);
    s = fma((double)n31, 0x1p7, s);
    return s;
}

struct Planes { u32 Mh, QA, QB, QC, Re, mO, mWW2, mU; };

// Bit-sliced f0 classification (validated rounds 2-4).
__device__ __forceinline__ Planes classes(int type, u32 Bh, u32 Bd,
                                          u32 Ch, u32 Cd, u32 Dh, u32 Dd) {
    Planes P;
    if (type <= 1) {
        u32 selh, seld, mainh, maind, subh, subd;
        if (type == 0) { selh=Bh; seld=Bd; mainh=Ch; maind=Cd; subh=Dh; subd=Dd; }
        else           { selh=Dh; seld=Dd; mainh=Bh; maind=Bd; subh=Ch; subd=Cd; }
        u32 selZ = ~selh, selO = selh & ~seld;
        u32 mainO = mainh & ~maind, subO = subh & ~subd;
        u32 mO  = (selZ & subO) | (selO & mainO);
        u32 mW  = (selZ & subd) | (selO & maind) | (seld & mainO);
        u32 mW2 = seld & maind;
        u32 tse = seld & ~mainh;
        u32 mTE = tse & subh;
        u32 mE  = tse & subd;
        P.mO = mO; P.mU = 0u;
        P.mWW2 = mW | mW2;
        P.Mh = mO | P.mWW2;
        P.QA = mW | mTE;
        P.QB = P.mWW2;
        P.QC = ~P.mWW2;
        P.Re = mE;
    } else if (type == 2) {
        u32 BZ=~Bh, CZ=~Ch, DZ=~Dh;
        u32 BO=Bh&~Bd, CO=Ch&~Cd, DO=Dh&~Dd;
        u32 x1Z = (BZ&CZ)|(BO&CO);
        u32 x1O = (BZ&CO)|(BO&CZ);
        u32 x1W = (BZ&Cd)|(Bd&CZ);
        u32 x1U = (Bh&Cd)|(Bd&Ch);
        u32 mO  = (x1Z&DO)|(x1O&DZ);
        u32 mW  = (x1Z&Dd)|(x1W&DZ);
        u32 mU  = (x1O&Dd)|(x1W&Dh)|(x1U&DZ);
        u32 mW2 = x1U&DO;
        u32 mW4 = x1U&Dd;
        P.mO = mO; P.mU = mU;
        P.mWW2 = mW | mW2;
        P.Mh = mO | mW | mW2 | mW4;
        P.QA = mW;
        P.QB = mW2 | mW | mU;
        P.QC = ~(mW | mW2 | mW4);
        P.Re = 0u;
    } else {
        u32 BZ=~Bh, CZ=~Ch, DZ=~Dh;
        u32 BO=Bh&~Bd, CO=Ch&~Cd, DO=Dh&~Dd;
        u32 oZ = BZ & DO;
        u32 oO = (BZ&DZ) | (BO&~Dd) | (Bd&DZ);
        u32 oW = (BO&Dd) | (Bd&Dh);
        u32 oT = BZ & Dd;
        u32 mO  = (CZ&oO)|(CO&oZ);
        u32 mW  = (CZ&oW)|(Cd&oZ);
        u32 mT  = CZ&oT;
        u32 mU  = (CO&oW)|(Cd&(oO|oW));
        u32 mW2 = Ch&oT;
        P.mO = mO; P.mU = mU;
        P.mWW2 = mW | mW2;
        P.Mh = mO | mW | mW2;
        P.QA = mW | mT;
        P.QB = mW2 | mW | mU;
        P.QC = ~(mW | mW2);
        P.Re = 0u;
    }
    return P;
}

// per-bit f0 value: v = n*2^-24 + cd (exact assembly)
__device__ __forceinline__ double vbit(const Planes& P, int k) {
#pragma clang fp contract(off)
    u32 hb = (P.Mh >> k) & 1u;
    u32 n = (hb << 24) + ((P.QA >> k) & 1u) + (((P.QB >> k) & 1u) << 1)
          + (((P.QC >> k) & 1u) << 2);
    double cd = ((P.Re >> k) & 1u) ? (-0x1p-22 - 0x1p-48) : -0x1p-22;
    return fma((double)n, 0x1p-24, cd);
}

// Slow chain with exact prefix: bits below kE are rounding-free (chain_fast
// theorem on an E-free prefix) -> closed-form integer; honest sequential fma
// from kE. ROUND-6 FIX: lanes with ReL==0 (dragged here by the wave ballot)
// use kE=29, which degenerates exactly to chain_fast.
__device__ double chain_slow(const Planes& P) {
#pragma clang fp contract(off)
    u32 ReL = P.Re & 0x1FFFFFFFu;
    int kE = (ReL == 0u) ? 29 : __builtin_ctz(ReL);
    u32 pm = (1u << kE) - 1u;           // kE in [0,29]
    u32 lo = (P.QA & pm) + ((P.QB & pm) << 1) + ((P.QC & pm) << 2);
    u64 I = (((u64)(P.Mh & pm)) << 24) + (u64)lo - ((4ull << kE) - 4ull);
    double S = fma((double)(u32)(I >> 32), 0x1p32, (double)(u32)I) * 0x1p-24;
    for (int k = kE; k < 32; ++k)
        S = fma(vbit(P, k), (double)(1u << k), S);
    return S;
}

// Fast chain, valid iff (Re & 0x1FFFFFFF)==0 (validated round 4).
__device__ __forceinline__ double chain_fast(const Planes& P) {
#pragma clang fp contract(off)
    const u32 M29 = 0x1FFFFFFFu;
    u32 lo = (P.QA & M29) + ((P.QB & M29) << 1) + ((P.QC & M29) << 2);
    u64 I = (((u64)(P.Mh & M29)) << 24) + (u64)lo - 0x7FFFFFFCull;
    double X = fma((double)(u32)(I >> 32), 0x1p32, (double)(u32)I);
    double accF = X * 0x1p-24;
    accF = fma(vbit(P, 29), 0x1p29, accF);
    accF = fma(vbit(P, 30), 0x1p30, accF);
    accF = fma(vbit(P, 31), 0x1p31, accF);
    return accF;
}

__device__ const u32 Ku[64] = {
    0xd76aa478u,0xe8c7b756u,0x242070dbu,0xc1bdceeeu,
    0xf57c0fafu,0x4787c62au,0xa8304613u,0xfd469501u,
    0x698098d8u,0x8b44f7afu,0xffff5bb1u,0x895cd7beu,
    0x6b901122u,0xfd987193u,0xa679438eu,0x49b40821u,
    0xf61e2562u,0xc040b340u,0x265e5a51u,0xe9b6c7aau,
    0xd62f105du,0x02441453u,0xd8a1e681u,0xe7d3fbc8u,
    0x21e1cde6u,0xc33707d6u,0xf4d50d87u,0x455a14edu,
    0xa9e3e905u,0xfcefa3f8u,0x676f02d9u,0x8d2a4c8au,
    0xfffa3942u,0x8771f681u,0x6d9d6122u,0xfde5380cu,
    0xa4beea44u,0x4bdecfa9u,0xf6bb4b60u,0xbebfbc70u,
    0x289b7ec6u,0xeaa127fau,0xd4ef3085u,0x04881d05u,
    0xd9d4d039u,0xe6db99e5u,0x1fa27cf8u,0xc4ac5665u,
    0xf4292244u,0x432aff97u,0xab9423a7u,0xfc93a039u,
    0x655b59c3u,0x8f0ccc92u,0xffeff47du,0x85845dd1u,
    0x6fa87e4fu,0xfe2ce6e0u,0xa3014314u,0x4e0811a1u,
    0xf7537e82u,0xbd3af235u,0x2ad7d2bbu,0xeb86d391u
};
__device__ const u32 Stab[64] = {
    7,12,17,22, 7,12,17,22, 7,12,17,22, 7,12,17,22,
    5, 9,14,20, 5, 9,14,20, 5, 9,14,20, 5, 9,14,20,
    4,11,16,23, 4,11,16,23, 4,11,16,23, 4,11,16,23,
    6,10,15,21, 6,10,15,21, 6,10,15,21, 6,10,15,21
};
__device__ const u32 PWt[16] = { 128u,0,0,0, 0,0,0,0, 0,0,0,0, 0,0,512u,0 };

// Soft round. WSEL: 0 -> LDS/scratch message word (block 0); 1 -> PW word (block 1).
#define ROUND(TYPE, WSEL, i, g)                                               \
    {                                                                         \
        Planes P = classes(TYPE, Bh, Bd, Ch, Cd, Dh, Dd);                     \
        u32 df1 = (P.mO & Ad) | (P.mWW2 & Ah) | (P.mU & ~Ah);                 \
        double accF;                                                          \
        if (TYPE >= 2) {                                                      \
            accF = chain_fast(P);                                             \
        } else if (__ballot((P.Re & 0x1FFFFFFFu) != 0u) == 0ull) {            \
            accF = chain_fast(P);                                             \
        } else {                                                              \
            accF = chain_slow(P);                                             \
        }                                                                     \
        double s1 = accF + vA; if (s1 >= 0x1p32) s1 -= 0x1p32;                \
        u32 h1 = (u32)s1, d1 = h1 & df1;                                      \
        double V1 = sum_packed(h1, d1);                                       \
        u32 Kv = Ku[i];                                                       \
        double s2 = V1 + (double)Kv; if (s2 >= 0x1p32) s2 -= 0x1p32;          \
        u32 h2 = (u32)s2, d2 = h2 & d1 & Kv;                                  \
        double V2 = sum_packed(h2, d2);                                       \
        u32 df3; double bv;                                                   \
        if (WSEL == 0) {                                                      \
            df3 = (~h2 & sd0[g]) | ((h2 & ~d2) & sd1[g])                      \
                | (d2 & sdw[g]);                                              \
            bv = lds_wv[g][tid];                                              \
        } else {                                                              \
            u32 pw = PWt[g];                                                  \
            df3 = d2 & pw;                                                    \
            bv = (double)pw;                                                  \
        }                                                                     \
        double s3 = V2 + bv; if (s3 >= 0x1p32) s3 -= 0x1p32;                  \
        u32 h3 = (u32)s3, d3 = h3 & df3;                                      \
        u32 sh = Stab[i];                                                     \
        u32 rh = rotl32(h3, sh), rd = rotl32(d3, sh);                         \
        double Vr = sum_packed(rh, rd);                                       \
        double s4 = vB + Vr; if (s4 >= 0x1p32) s4 -= 0x1p32;                  \
        u32 h4 = (u32)s4;                                                     \
        u32 d4 = h4 & (Bh & rh) & (Bd | rd);                                  \
        double V4 = sum_packed(h4, d4);                                       \
        Ah = Dh; Ad = Dd; vA = vD;                                            \
        Dh = Ch; Dd = Cd; vD = vC;                                            \
        Ch = Bh; Cd = Bd; vC = vB;                                            \
        Bh = h4; Bd = d4; vB = V4;                                            \
    }

// Pure-integer round: valid when all dirt masks are zero (exactly equals the
// reference's f64 semantics on hard bits — all f32/f64 ops exact).
#define INTROUND(TYPE, i, g)                                                  \
    {                                                                         \
        u32 f;                                                                \
        if (TYPE == 0)      f = (Bh & Ch) | (~Bh & Dh);                       \
        else if (TYPE == 1) f = (Dh & Bh) | (~Dh & Ch);                       \
        else if (TYPE == 2) f = Bh ^ Ch ^ Dh;                                 \
        else                f = Ch ^ (Bh | ~Dh);                              \
        f += Ah + Ku[i] + PWt[g];                                             \
        u32 nb = Bh + rotl32(f, Stab[i]);                                     \
        Ah = Dh; Dh = Ch; Ch = Bh; Bh = nb;                                   \
    }

// Block-1 round: sticky wave-uniform switch to int mode once dirt-free.
#define B1ROUND(TYPE, i, g)                                                   \
    {                                                                         \
        if (!intm) intm = (__ballot((Ad | Bd | Cd | Dd) != 0u) == 0ull);      \
        if (intm) INTROUND(TYPE, i, g)                                        \
        else      ROUND(TYPE, 1, i, g)                                        \
    }

__global__ __launch_bounds__(128, 4) void softmd5_kernel(
    const float* __restrict__ msg, float* __restrict__ out, int B)
{
#pragma clang fp contract(off)
    __shared__ double lds_wv[16][128];   // 16 KB total LDS (was 40 KB)

    // Dirty-mask planes: per-thread scratch (runtime-indexed local arrays ->
    // private segment). 192 B/lane, lane-interleaved (coalesced when all
    // lanes read the same g), L2-resident. This is what bought occupancy.
    u32 sd0[16], sd1[16], sdw[16];

    const int tid = threadIdx.x;
    const int e = blockIdx.x * 128 + tid;
    if (e >= B) return;

    const float* row = msg + (size_t)e * 512;
    const float4* r4 = reinterpret_cast<const float4*>(row);

    // per-word precompute: f64 value (sequential k=0..31) + 3 dirty masks
    for (int w = 0; w < 16; ++w) {
        double acc = 0.0;
        u32 m0 = 0, m1 = 0, mw = 0;
        #pragma unroll
        for (int q = 0; q < 8; ++q) {
            float4 v = r4[w * 8 + q];
            const int k = 4 * q;
            acc = fma((double)v.x, (double)(1u << (k + 0)), acc);
            acc = fma((double)v.y, (double)(1u << (k + 1)), acc);
            acc = fma((double)v.z, (double)(1u << (k + 2)), acc);
            acc = fma((double)v.w, (double)(1u << (k + 3)), acc);
            m0 |= dirty0(v.x) << (k+0); m0 |= dirty0(v.y) << (k+1);
            m0 |= dirty0(v.z) << (k+2); m0 |= dirty0(v.w) << (k+3);
            m1 |= dirty1(v.x) << (k+0); m1 |= dirty1(v.y) << (k+1);
            m1 |= dirty1(v.z) << (k+2); m1 |= dirty1(v.w) << (k+3);
            mw |= dirtyw(v.x) << (k+0); mw |= dirtyw(v.y) << (k+1);
            mw |= dirtyw(v.z) << (k+2); mw |= dirtyw(v.w) << (k+3);
        }
        lds_wv[w][tid] = acc;
        sd0[w] = m0;
        sd1[w] = m1;
        sdw[w] = mw;
    }

    u32 Ah = 0x67452301u, Ad = 0u;
    u32 Bh = 0xefcdab89u, Bd = 0u;
    u32 Ch = 0x98badcfeu, Cd = 0u;
    u32 Dh = 0x10325476u, Dd = 0u;
    double vA = (double)Ah, vB = (double)Bh, vC = (double)Ch, vD = (double)Dh;

    // ================= block 0 (fractional message words) =================
    {
        const u32 sAh=Ah, sAd=Ad, sBh=Bh, sBd=Bd;
        const u32 sCh=Ch, sCd=Cd, sDh=Dh, sDd=Dd;
        const double sVA=vA, sVB=vB, sVC=vC, sVD=vD;

        #pragma unroll 1
        for (int i = 0; i < 16; ++i) ROUND(0, 0, i, i)
        #pragma unroll 1
        for (int i = 16; i < 32; ++i) ROUND(1, 0, i, (5 * i + 1) & 15)
        #pragma unroll 1
        for (int i = 32; i < 48; ++i) ROUND(2, 0, i, (3 * i + 5) & 15)
        #pragma unroll 1
        for (int i = 48; i < 64; ++i) ROUND(3, 0, i, (7 * i) & 15)

        {
            double s = sVA + vA; if (s >= 0x1p32) s -= 0x1p32;
            u32 h = (u32)s; u32 dd = h & (sAh & Ah) & (sAd | Ad);
            Ah = h; Ad = dd; vA = sum_packed(Ah, Ad);
        }
        {
            double s = sVB + vB; if (s >= 0x1p32) s -= 0x1p32;
            u32 h = (u32)s; u32 dd = h & (sBh & Bh) & (sBd | Bd);
            Bh = h; Bd = dd; vB = sum_packed(Bh, Bd);
        }
        {
            double s = sVC + vC; if (s >= 0x1p32) s -= 0x1p32;
            u32 h = (u32)s; u32 dd = h & (sCh & Ch) & (sCd | Cd);
            Ch = h; Cd = dd; vC = sum_packed(Ch, Cd);
        }
        {
            double s = sVD + vD; if (s >= 0x1p32) s -= 0x1p32;
            u32 h = (u32)s; u32 dd = h & (sDh & Dh) & (sDd | Dd);
            Dh = h; Dd = dd; vD = sum_packed(Dh, Dd);
        }
    }

    // ================= block 1 (hard pad words; dirt decays) ==============
    {
        const u32 sAh=Ah, sAd=Ad, sBh=Bh, sBd=Bd;
        const u32 sCh=Ch, sCd=Cd, sDh=Dh, sDd=Dd;
        const double sVA=vA, sVB=vB, sVC=vC, sVD=vD;
        bool intm = false;

        #pragma unroll 1
        for (int i = 0; i < 16; ++i) B1ROUND(0, i, i)
        #pragma unroll 1
        for (int i = 16; i < 32; ++i) B1ROUND(1, i, (5 * i + 1) & 15)
        #pragma unroll 1
        for (int i = 32; i < 48; ++i) B1ROUND(2, i, (3 * i + 5) & 15)
        #pragma unroll 1
        for (int i = 48; i < 64; ++i) B1ROUND(3, i, (7 * i) & 15)

        if (intm) {   // dirt-free: values are the plain integers
            vA = (double)Ah; vB = (double)Bh; vC = (double)Ch; vD = (double)Dh;
        }

        {
            double s = sVA + vA; if (s >= 0x1p32) s -= 0x1p32;
            u32 h = (u32)s; u32 dd = h & (sAh & Ah) & (sAd | Ad);
            Ah = h; Ad = dd;
        }
        {
            double s = sVB + vB; if (s >= 0x1p32) s -= 0x1p32;
            u32 h = (u32)s; u32 dd = h & (sBh & Bh) & (sBd | Bd);
            Bh = h; Bd = dd;
        }
        {
            double s = sVC + vC; if (s >= 0x1p32) s -= 0x1p32;
            u32 h = (u32)s; u32 dd = h & (sCh & Ch) & (sCd | Cd);
            Ch = h; Cd = dd;
        }
        {
            double s = sVD + vD; if (s >= 0x1p32) s -= 0x1p32;
            u32 h = (u32)s; u32 dd = h & (sDh & Dh) & (sDd | Dd);
            Dh = h; Dd = dd;
        }
    }

    // ---- emit 128 floats: hard bits (|w-1|=6e-8 << 0.02 threshold)
    float4* orow = reinterpret_cast<float4*>(out) + (size_t)e * 32;
    const u32 H[4] = {Ah, Bh, Ch, Dh};
    #pragma unroll
    for (int hh = 0; hh < 4; ++hh) {
        #pragma unroll
        for (int q = 0; q < 8; ++q) {
            float4 v;
            v.x = (float)((H[hh] >> (q * 4 + 0)) & 1u);
            v.y = (float)((H[hh] >> (q * 4 + 1)) & 1u);
            v.z = (float)((H[hh] >> (q * 4 + 2)) & 1u);
            v.w = (float)((H[hh] >> (q * 4 + 3)) & 1u);
            orow[hh * 8 + q] = v;
        }
    }
}

extern "C" void kernel_launch(void* const* d_in, const int* in_sizes, int n_in,
                              void* d_out, int out_size, void* d_ws, size_t ws_size,
                              hipStream_t stream) {
    (void)n_in; (void)d_ws; (void)ws_size; (void)out_size;
    const float* msg = (const float*)d_in[0];
    float* out = (float*)d_out;
    const int B = in_sizes[0] / 512;
    const int block = 128;
    const int grid = (B + block - 1) / block;
    softmd5_kernel<<<grid, block, 0, stream>>>(msg, out, B);
}

// Round 2
// 477.957 us; speedup vs baseline: 1.0523x; 1.0523x over previous
//
#include <hip/hip_runtime.h>
#include <stdint.h>
#include <stddef.h>

// Bit-exact emulation of the reference's f32/f64 rounding. Contraction would
// change rounding of the literal f32 chains -> force it off globally.
#pragma clang fp contract(off)

typedef unsigned int u32;
typedef unsigned long long u64;

// ===========================================================================
// Validated machinery (rounds 2-4): state bits in {Z=0, O=1, W=1-2^-24},
// packed (hard,dirty) masks; f0 classes {Z,O,W,W2,W4,T,U,E} as planes
// Mh/QA/QB/QC/Re (v = h + (QA+2QB+4QC-4)*2^-24 - Re*2^-48).
//
// Round-7 lesson (occupancy): total parallelism is B=131072 msgs -> 2048
// waves -> EXACTLY 2 waves/SIMD across the whole chip. Occupancy is
// grid-capped at 25%; LDS 40KB/block (4 blocks/CU) was never the binding
// limit. Masks in scratch tripled HBM writes and regressed 222->245 us.
// Reverted: masks back in LDS, launch_bounds(128,2).
//
// Round-8 change (slow-chain): with random inputs P.Re is dense -> every
// type-0/1 round takes the slow chain for the whole wave, and min(kE) over
// 64 lanes ~ 0 -> the old per-lane-kE divergent loop ran ~32 iters anyway,
// paying per-lane loop control + per-lane (1u<<k)+cvt + cndmask'd cd each
// iter. chain_slow(kE=0) IS the honest full loop (prefix theorem), so use a
// UNIFORM rolled k=0..31 loop: SGPR loop control (SALU pipe), 2^k built as
// ((1023+k)<<52) in SALU, cd select = 1-bit OR into mantissa bit 26
// (-2^-22 vs -2^-22-2^-48 differ in exactly that bit). ~12 VALU/iter vs
// ~19-20. Also KuD[] kills one v_cvt_f64_u32 per round.
// ===========================================================================

__device__ __forceinline__ u32 rotl32(u32 x, u32 n) {
    return (x << n) | (x >> (32u - n));
}

#define WF   0x1.fffffep-1f   /* w  = 1-2^-24 */
#define TWOW 0x1.fffffep+0f   /* 2w = 2-2^-23 */

// dirty flags for soft_add32(x, y) with raw float y, x in {0,1,w}
__device__ __forceinline__ u32 dirty0(float y) {
#pragma clang fp contract(off)
    float p = 0.5f * y;
    float t = 1.0f + p;
    return (u32)((t - p) != 1.0f);
}
__device__ __forceinline__ u32 dirty1(float y) {
#pragma clang fp contract(off)
    float u = 1.0f + y;
    float v = y + y;
    float xr = u - v;
    float p = 0.5f * xr;
    float t = 1.0f + p;
    return (u32)((t - p) != 1.0f);
}
__device__ __forceinline__ u32 dirtyw(float y) {
#pragma clang fp contract(off)
    float u = WF + y;
    float v = TWOW * y;
    float xr = u - v;
    float p = 0.5f * xr;
    float t = 1.0f + p;
    return (u32)((t - p) != 1.0f);
}

// Sequential f64 bit-sum of a packed {0,1,w} word (validated).
__device__ __forceinline__ double sum_packed(u32 h, u32 d) {
#pragma clang fp contract(off)
    double s = fma((double)(d & 0x1FFFFFFFu), -0x1p-24,
                   (double)(h & 0x1FFFFFFFu));
    int n29 = (int)(((h >> 29) & 1u) << 24) - (int)((d >> 29) & 1u);
    s = fma((double)n29, 0x1p5, s);
    int n30 = (int)(((h >> 30) & 1u) << 24) - (int)((d >> 30) & 1u);
    s = fma((double)n30, 0x1p6, s);
    int n31 = (int)((h >> 31) << 24) - (int)(d >> 31);
    s = fma((double)n31, 0x1p7, s);
    return s;
}

struct Planes { u32 Mh, QA, QB, QC, Re, mO, mWW2, mU; };

// Bit-sliced f0 classification (validated rounds 2-4).
__device__ __forceinline__ Planes classes(int type, u32 Bh, u32 Bd,
                                          u32 Ch, u32 Cd, u32 Dh, u32 Dd) {
    Planes P;
    if (type <= 1) {
        u32 selh, seld, mainh, maind, subh, subd;
        if (type == 0) { selh=Bh; seld=Bd; mainh=Ch; maind=Cd; subh=Dh; subd=Dd; }
        else           { selh=Dh; seld=Dd; mainh=Bh; maind=Bd; subh=Ch; subd=Cd; }
        u32 selZ = ~selh, selO = selh & ~seld;
        u32 mainO = mainh & ~maind, subO = subh & ~subd;
        u32 mO  = (selZ & subO) | (selO & mainO);
        u32 mW  = (selZ & subd) | (selO & maind) | (seld & mainO);
        u32 mW2 = seld & maind;
        u32 tse = seld & ~mainh;
        u32 mTE = tse & subh;
        u32 mE  = tse & subd;
        P.mO = mO; P.mU = 0u;
        P.mWW2 = mW | mW2;
        P.Mh = mO | P.mWW2;
        P.QA = mW | mTE;
        P.QB = P.mWW2;
        P.QC = ~P.mWW2;
        P.Re = mE;
    } else if (type == 2) {
        u32 BZ=~Bh, CZ=~Ch, DZ=~Dh;
        u32 BO=Bh&~Bd, CO=Ch&~Cd, DO=Dh&~Dd;
        u32 x1Z = (BZ&CZ)|(BO&CO);
        u32 x1O = (BZ&CO)|(BO&CZ);
        u32 x1W = (BZ&Cd)|(Bd&CZ);
        u32 x1U = (Bh&Cd)|(Bd&Ch);
        u32 mO  = (x1Z&DO)|(x1O&DZ);
        u32 mW  = (x1Z&Dd)|(x1W&DZ);
        u32 mU  = (x1O&Dd)|(x1W&Dh)|(x1U&DZ);
        u32 mW2 = x1U&DO;
        u32 mW4 = x1U&Dd;
        P.mO = mO; P.mU = mU;
        P.mWW2 = mW | mW2;
        P.Mh = mO | mW | mW2 | mW4;
        P.QA = mW;
        P.QB = mW2 | mW | mU;
        P.QC = ~(mW | mW2 | mW4);
        P.Re = 0u;
    } else {
        u32 BZ=~Bh, CZ=~Ch, DZ=~Dh;
        u32 BO=Bh&~Bd, CO=Ch&~Cd, DO=Dh&~Dd;
        u32 oZ = BZ & DO;
        u32 oO = (BZ&DZ) | (BO&~Dd) | (Bd&DZ);
        u32 oW = (BO&Dd) | (Bd&Dh);
        u32 oT = BZ & Dd;
        u32 mO  = (CZ&oO)|(CO&oZ);
        u32 mW  = (CZ&oW)|(Cd&oZ);
        u32 mT  = CZ&oT;
        u32 mU  = (CO&oW)|(Cd&(oO|oW));
        u32 mW2 = Ch&oT;
        P.mO = mO; P.mU = mU;
        P.mWW2 = mW | mW2;
        P.Mh = mO | mW | mW2;
        P.QA = mW | mT;
        P.QB = mW2 | mW | mU;
        P.QC = ~(mW | mW2);
        P.Re = 0u;
    }
    return P;
}

// Honest uniform chain: S = sum_k vbit(k)*2^k with per-step f64 rounding,
// k = 0..31. Equals chain_slow(kE=0) for every lane (prefix theorem:
// honest processing of an E-free prefix is rounding-free), so it is valid
// for ALL lanes regardless of Re. Uniform k -> loop control + 2^k on the
// SALU pipe; cd built by OR'ing Re_k into mantissa bit 26.
__device__ __forceinline__ double chain_honest(const Planes& P) {
#pragma clang fp contract(off)
    double S = 0.0;
    #pragma unroll 1
    for (int k = 0; k < 32; ++k) {
        u32 hb = (P.Mh >> k) & 1u;
        u32 n  = (hb << 24) + ((P.QA >> k) & 1u) + (((P.QB >> k) & 1u) << 1)
               + (((P.QC >> k) & 1u) << 2);
        // cd = -2^-22 - Re_k*2^-48 ; the two values differ only in mantissa
        // bit 26 (0xBE90000000000000 vs 0xBE90000004000000).
        u64 cdbits = 0xBE90000000000000ull | ((u64)((P.Re >> k) & 1u) << 26);
        double cd = __builtin_bit_cast(double, cdbits);
        double term = fma((double)n, 0x1p-24, cd);   // exact (<=53 bits)
        double p2k = __builtin_bit_cast(double, ((u64)(1023 + k)) << 52); // 2^k
        S = fma(term, p2k, S);                       // single rounding/step
    }
    return S;
}

// Fast chain, valid iff (Re & 0x1FFFFFFF)==0 (validated round 4).
__device__ __forceinline__ double chain_fast(const Planes& P) {
#pragma clang fp contract(off)
    u32 hb29 = (P.Mh >> 29) & 1u;
    u32 n29 = (hb29 << 24) + ((P.QA >> 29) & 1u) + (((P.QB >> 29) & 1u) << 1)
            + (((P.QC >> 29) & 1u) << 2);
    u32 hb30 = (P.Mh >> 30) & 1u;
    u32 n30 = (hb30 << 24) + ((P.QA >> 30) & 1u) + (((P.QB >> 30) & 1u) << 1)
            + (((P.QC >> 30) & 1u) << 2);
    u32 hb31 = (P.Mh >> 31) & 1u;
    u32 n31 = (hb31 << 24) + ((P.QA >> 31) & 1u) + (((P.QB >> 31) & 1u) << 1)
            + (((P.QC >> 31) & 1u) << 2);
    const u32 M29 = 0x1FFFFFFFu;
    u32 lo = (P.QA & M29) + ((P.QB & M29) << 1) + ((P.QC & M29) << 2);
    u64 I = (((u64)(P.Mh & M29)) << 24) + (u64)lo - 0x7FFFFFFCull;
    double X = fma((double)(u32)(I >> 32), 0x1p32, (double)(u32)I);
    double accF = X * 0x1p-24;
    {
        u64 cdb = 0xBE90000000000000ull | ((u64)((P.Re >> 29) & 1u) << 26);
        double t = fma((double)n29, 0x1p-24, __builtin_bit_cast(double, cdb));
        accF = fma(t, 0x1p29, accF);
    }
    {
        u64 cdb = 0xBE90000000000000ull | ((u64)((P.Re >> 30) & 1u) << 26);
        double t = fma((double)n30, 0x1p-24, __builtin_bit_cast(double, cdb));
        accF = fma(t, 0x1p30, accF);
    }
    {
        u64 cdb = 0xBE90000000000000ull | ((u64)((P.Re >> 31) & 1u) << 26);
        double t = fma((double)n31, 0x1p-24, __builtin_bit_cast(double, cdb));
        accF = fma(t, 0x1p31, accF);
    }
    return accF;
}

__device__ const u32 Ku[64] = {
    0xd76aa478u,0xe8c7b756u,0x242070dbu,0xc1bdceeeu,
    0xf57c0fafu,0x4787c62au,0xa8304613u,0xfd469501u,
    0x698098d8u,0x8b44f7afu,0xffff5bb1u,0x895cd7beu,
    0x6b901122u,0xfd987193u,0xa679438eu,0x49b40821u,
    0xf61e2562u,0xc040b340u,0x265e5a51u,0xe9b6c7aau,
    0xd62f105du,0x02441453u,0xd8a1e681u,0xe7d3fbc8u,
    0x21e1cde6u,0xc33707d6u,0xf4d50d87u,0x455a14edu,
    0xa9e3e905u,0xfcefa3f8u,0x676f02d9u,0x8d2a4c8au,
    0xfffa3942u,0x8771f681u,0x6d9d6122u,0xfde5380cu,
    0xa4beea44u,0x4bdecfa9u,0xf6bb4b60u,0xbebfbc70u,
    0x289b7ec6u,0xeaa127fau,0xd4ef3085u,0x04881d05u,
    0xd9d4d039u,0xe6db99e5u,0x1fa27cf8u,0xc4ac5665u,
    0xf4292244u,0x432aff97u,0xab9423a7u,0xfc93a039u,
    0x655b59c3u,0x8f0ccc92u,0xffeff47du,0x85845dd1u,
    0x6fa87e4fu,0xfe2ce6e0u,0xa3014314u,0x4e0811a1u,
    0xf7537e82u,0xbd3af235u,0x2ad7d2bbu,0xeb86d391u
};
// Same constants as exact doubles: kills a v_cvt_f64_u32 per round.
__device__ const double KuD[64] = {
    (double)0xd76aa478u,(double)0xe8c7b756u,(double)0x242070dbu,(double)0xc1bdceeeu,
    (double)0xf57c0fafu,(double)0x4787c62au,(double)0xa8304613u,(double)0xfd469501u,
    (double)0x698098d8u,(double)0x8b44f7afu,(double)0xffff5bb1u,(double)0x895cd7beu,
    (double)0x6b901122u,(double)0xfd987193u,(double)0xa679438eu,(double)0x49b40821u,
    (double)0xf61e2562u,(double)0xc040b340u,(double)0x265e5a51u,(double)0xe9b6c7aau,
    (double)0xd62f105du,(double)0x02441453u,(double)0xd8a1e681u,(double)0xe7d3fbc8u,
    (double)0x21e1cde6u,(double)0xc33707d6u,(double)0xf4d50d87u,(double)0x455a14edu,
    (double)0xa9e3e905u,(double)0xfcefa3f8u,(double)0x676f02d9u,(double)0x8d2a4c8au,
    (double)0xfffa3942u,(double)0x8771f681u,(double)0x6d9d6122u,(double)0xfde5380cu,
    (double)0xa4beea44u,(double)0x4bdecfa9u,(double)0xf6bb4b60u,(double)0xbebfbc70u,
    (double)0x289b7ec6u,(double)0xeaa127fau,(double)0xd4ef3085u,(double)0x04881d05u,
    (double)0xd9d4d039u,(double)0xe6db99e5u,(double)0x1fa27cf8u,(double)0xc4ac5665u,
    (double)0xf4292244u,(double)0x432aff97u,(double)0xab9423a7u,(double)0xfc93a039u,
    (double)0x655b59c3u,(double)0x8f0ccc92u,(double)0xffeff47du,(double)0x85845dd1u,
    (double)0x6fa87e4fu,(double)0xfe2ce6e0u,(double)0xa3014314u,(double)0x4e0811a1u,
    (double)0xf7537e82u,(double)0xbd3af235u,(double)0x2ad7d2bbu,(double)0xeb86d391u
};
__device__ const u32 Stab[64] = {
    7,12,17,22, 7,12,17,22, 7,12,17,22, 7,12,17,22,
    5, 9,14,20, 5, 9,14,20, 5, 9,14,20, 5, 9,14,20,
    4,11,16,23, 4,11,16,23, 4,11,16,23, 4,11,16,23,
    6,10,15,21, 6,10,15,21, 6,10,15,21, 6,10,15,21
};
__device__ const u32 PWt[16] = { 128u,0,0,0, 0,0,0,0, 0,0,0,0, 0,0,512u,0 };

// Soft round. WSEL: 0 -> LDS message word (block 0); 1 -> PW word (block 1).
#define ROUND(TYPE, WSEL, i, g)                                               \
    {                                                                         \
        Planes P = classes(TYPE, Bh, Bd, Ch, Cd, Dh, Dd);                     \
        u32 df1 = (P.mO & Ad) | (P.mWW2 & Ah) | (P.mU & ~Ah);                 \
        double accF;                                                          \
        if (TYPE >= 2) {                                                      \
            accF = chain_fast(P);                                             \
        } else if (__ballot((P.Re & 0x1FFFFFFFu) != 0u) == 0ull) {            \
            accF = chain_fast(P);                                             \
        } else {                                                              \
            accF = chain_honest(P);                                           \
        }                                                                     \
        double s1 = accF + vA; if (s1 >= 0x1p32) s1 -= 0x1p32;                \
        u32 h1 = (u32)s1, d1 = h1 & df1;                                      \
        double V1 = sum_packed(h1, d1);                                       \
        u32 Kv = Ku[i];                                                       \
        double s2 = V1 + KuD[i]; if (s2 >= 0x1p32) s2 -= 0x1p32;              \
        u32 h2 = (u32)s2, d2 = h2 & d1 & Kv;                                  \
        double V2 = sum_packed(h2, d2);                                       \
        u32 df3; double bv;                                                   \
        if (WSEL == 0) {                                                      \
            df3 = (~h2 & lds_d0[g][tid]) | ((h2 & ~d2) & lds_d1[g][tid])      \
                | (d2 & lds_dw[g][tid]);                                      \
            bv = lds_wv[g][tid];                                              \
        } else {                                                              \
            u32 pw = PWt[g];                                                  \
            df3 = d2 & pw;                                                    \
            bv = (double)pw;                                                  \
        }                                                                     \
        double s3 = V2 + bv; if (s3 >= 0x1p32) s3 -= 0x1p32;                  \
        u32 h3 = (u32)s3, d3 = h3 & df3;                                      \
        u32 sh = Stab[i];                                                     \
        u32 rh = rotl32(h3, sh), rd = rotl32(d3, sh);                         \
        double Vr = sum_packed(rh, rd);                                       \
        double s4 = vB + Vr; if (s4 >= 0x1p32) s4 -= 0x1p32;                  \
        u32 h4 = (u32)s4;                                                     \
        u32 d4 = h4 & (Bh & rh) & (Bd | rd);                                  \
        double V4 = sum_packed(h4, d4);                                       \
        Ah = Dh; Ad = Dd; vA = vD;                                            \
        Dh = Ch; Dd = Cd; vD = vC;                                            \
        Ch = Bh; Cd = Bd; vC = vB;                                            \
        Bh = h4; Bd = d4; vB = V4;                                            \
    }

// Pure-integer round: valid when all dirt masks are zero (exactly equals the
// reference's f64 semantics on hard bits — all f32/f64 ops exact).
#define INTROUND(TYPE, i, g)                                                  \
    {                                                                         \
        u32 f;                                                                \
        if (TYPE == 0)      f = (Bh & Ch) | (~Bh & Dh);                       \
        else if (TYPE == 1) f = (Dh & Bh) | (~Dh & Ch);                       \
        else if (TYPE == 2) f = Bh ^ Ch ^ Dh;                                 \
        else                f = Ch ^ (Bh | ~Dh);                              \
        f += Ah + Ku[i] + PWt[g];                                             \
        u32 nb = Bh + rotl32(f, Stab[i]);                                     \
        Ah = Dh; Dh = Ch; Ch = Bh; Bh = nb;                                   \
    }

// Block-1 round: sticky wave-uniform switch to int mode once dirt-free.
#define B1ROUND(TYPE, i, g)                                                   \
    {                                                                         \
        if (!intm) intm = (__ballot((Ad | Bd | Cd | Dd) != 0u) == 0ull);      \
        if (intm) INTROUND(TYPE, i, g)                                        \
        else      ROUND(TYPE, 1, i, g)                                        \
    }

__global__ __launch_bounds__(128, 2) void softmd5_kernel(
    const float* __restrict__ msg, float* __restrict__ out, int B)
{
#pragma clang fp contract(off)
    __shared__ double lds_wv[16][128];   // 16 KB
    __shared__ u32 lds_d0[16][128];      // 8 KB
    __shared__ u32 lds_d1[16][128];      // 8 KB
    __shared__ u32 lds_dw[16][128];      // 8 KB  => 40 KB total (grid-capped
                                         // occupancy: 4 blocks/CU resident,
                                         // LDS is free real estate here)

    const int tid = threadIdx.x;
    const int e = blockIdx.x * 128 + tid;
    if (e >= B) return;

    const float* row = msg + (size_t)e * 512;
    const float4* r4 = reinterpret_cast<const float4*>(row);

    // per-word precompute: f64 value (sequential k=0..31) + 3 dirty masks
    for (int w = 0; w < 16; ++w) {
        double acc = 0.0;
        u32 m0 = 0, m1 = 0, mw = 0;
        #pragma unroll
        for (int q = 0; q < 8; ++q) {
            float4 v = r4[w * 8 + q];
            const int k = 4 * q;
            acc = fma((double)v.x, (double)(1u << (k + 0)), acc);
            acc = fma((double)v.y, (double)(1u << (k + 1)), acc);
            acc = fma((double)v.z, (double)(1u << (k + 2)), acc);
            acc = fma((double)v.w, (double)(1u << (k + 3)), acc);
            m0 |= dirty0(v.x) << (k+0); m0 |= dirty0(v.y) << (k+1);
            m0 |= dirty0(v.z) << (k+2); m0 |= dirty0(v.w) << (k+3);
            m1 |= dirty1(v.x) << (k+0); m1 |= dirty1(v.y) << (k+1);
            m1 |= dirty1(v.z) << (k+2); m1 |= dirty1(v.w) << (k+3);
            mw |= dirtyw(v.x) << (k+0); mw |= dirtyw(v.y) << (k+1);
            mw |= dirtyw(v.z) << (k+2); mw |= dirtyw(v.w) << (k+3);
        }
        lds_wv[w][tid] = acc;
        lds_d0[w][tid] = m0;
        lds_d1[w][tid] = m1;
        lds_dw[w][tid] = mw;
    }

    u32 Ah = 0x67452301u, Ad = 0u;
    u32 Bh = 0xefcdab89u, Bd = 0u;
    u32 Ch = 0x98badcfeu, Cd = 0u;
    u32 Dh = 0x10325476u, Dd = 0u;
    double vA = (double)Ah, vB = (double)Bh, vC = (double)Ch, vD = (double)Dh;

    // ================= block 0 (fractional message words) =================
    {
        const u32 sAh=Ah, sAd=Ad, sBh=Bh, sBd=Bd;
        const u32 sCh=Ch, sCd=Cd, sDh=Dh, sDd=Dd;
        const double sVA=vA, sVB=vB, sVC=vC, sVD=vD;

        #pragma unroll 1
        for (int i = 0; i < 16; ++i) ROUND(0, 0, i, i)
        #pragma unroll 1
        for (int i = 16; i < 32; ++i) ROUND(1, 0, i, (5 * i + 1) & 15)
        #pragma unroll 1
        for (int i = 32; i < 48; ++i) ROUND(2, 0, i, (3 * i + 5) & 15)
        #pragma unroll 1
        for (int i = 48; i < 64; ++i) ROUND(3, 0, i, (7 * i) & 15)

        {
            double s = sVA + vA; if (s >= 0x1p32) s -= 0x1p32;
            u32 h = (u32)s; u32 dd = h & (sAh & Ah) & (sAd | Ad);
            Ah = h; Ad = dd; vA = sum_packed(Ah, Ad);
        }
        {
            double s = sVB + vB; if (s >= 0x1p32) s -= 0x1p32;
            u32 h = (u32)s; u32 dd = h & (sBh & Bh) & (sBd | Bd);
            Bh = h; Bd = dd; vB = sum_packed(Bh, Bd);
        }
        {
            double s = sVC + vC; if (s >= 0x1p32) s -= 0x1p32;
            u32 h = (u32)s; u32 dd = h & (sCh & Ch) & (sCd | Cd);
            Ch = h; Cd = dd; vC = sum_packed(Ch, Cd);
        }
        {
            double s = sVD + vD; if (s >= 0x1p32) s -= 0x1p32;
            u32 h = (u32)s; u32 dd = h & (sDh & Dh) & (sDd | Dd);
            Dh = h; Dd = dd; vD = sum_packed(Dh, Dd);
        }
    }

    // ================= block 1 (hard pad words; dirt decays) ==============
    {
        const u32 sAh=Ah, sAd=Ad, sBh=Bh, sBd=Bd;
        const u32 sCh=Ch, sCd=Cd, sDh=Dh, sDd=Dd;
        const double sVA=vA, sVB=vB, sVC=vC, sVD=vD;
        bool intm = false;

        #pragma unroll 1
        for (int i = 0; i < 16; ++i) B1ROUND(0, i, i)
        #pragma unroll 1
        for (int i = 16; i < 32; ++i) B1ROUND(1, i, (5 * i + 1) & 15)
        #pragma unroll 1
        for (int i = 32; i < 48; ++i) B1ROUND(2, i, (3 * i + 5) & 15)
        #pragma unroll 1
        for (int i = 48; i < 64; ++i) B1ROUND(3, i, (7 * i) & 15)

        if (intm) {   // dirt-free: values are the plain integers
            vA = (double)Ah; vB = (double)Bh; vC = (double)Ch; vD = (double)Dh;
        }

        {
            double s = sVA + vA; if (s >= 0x1p32) s -= 0x1p32;
            u32 h = (u32)s; u32 dd = h & (sAh & Ah) & (sAd | Ad);
            Ah = h; Ad = dd;
        }
        {
            double s = sVB + vB; if (s >= 0x1p32) s -= 0x1p32;
            u32 h = (u32)s; u32 dd = h & (sBh & Bh) & (sBd | Bd);
            Bh = h; Bd = dd;
        }
        {
            double s = sVC + vC; if (s >= 0x1p32) s -= 0x1p32;
            u32 h = (u32)s; u32 dd = h & (sCh & Ch) & (sCd | Cd);
            Ch = h; Cd = dd;
        }
        {
            double s = sVD + vD; if (s >= 0x1p32) s -= 0x1p32;
            u32 h = (u32)s; u32 dd = h & (sDh & Dh) & (sDd | Dd);
            Dh = h; Dd = dd;
        }
    }

    // ---- emit 128 floats: hard bits (|w-1|=6e-8 << 0.02 threshold)
    float4* orow = reinterpret_cast<float4*>(out) + (size_t)e * 32;
    const u32 H[4] = {Ah, Bh, Ch, Dh};
    #pragma unroll
    for (int hh = 0; hh < 4; ++hh) {
        #pragma unroll
        for (int q = 0; q < 8; ++q) {
            float4 v;
            v.x = (float)((H[hh] >> (q * 4 + 0)) & 1u);
            v.y = (float)((H[hh] >> (q * 4 + 1)) & 1u);
            v.z = (float)((H[hh] >> (q * 4 + 2)) & 1u);
            v.w = (float)((H[hh] >> (q * 4 + 3)) & 1u);
            orow[hh * 8 + q] = v;
        }
    }
}

extern "C" void kernel_launch(void* const* d_in, const int* in_sizes, int n_in,
                              void* d_out, int out_size, void* d_ws, size_t ws_size,
                              hipStream_t stream) {
    (void)n_in; (void)d_ws; (void)ws_size; (void)out_size;
    const float* msg = (const float*)d_in[0];
    float* out = (float*)d_out;
    const int B = in_sizes[0] / 512;
    const int block = 128;
    const int grid = (B + block - 1) / block;
    softmd5_kernel<<<grid, block, 0, stream>>>(msg, out, B);
}